// Round 2
// baseline (216.130 us; speedup 1.0000x reference)
//
#include <hip/hip_runtime.h>
#include <hip/hip_bf16.h>
#include <math.h>
#include <stdint.h>

typedef __attribute__((ext_vector_type(8))) short short8;
typedef __attribute__((ext_vector_type(4))) float float4v;

#define DEV static __device__ __forceinline__

DEV float bflo(unsigned int u) { union { unsigned int i; float f; } v; v.i = u << 16; return v.f; }
DEV float bfhi(unsigned int u) { union { unsigned int i; float f; } v; v.i = u & 0xffff0000u; return v.f; }
DEV unsigned short f2bf(float f) {
    union { float f; unsigned int i; } v; v.f = f;
    unsigned int x = v.i;
    return (unsigned short)((x + 0x7fffu + ((x >> 16) & 1u)) >> 16);
}
DEV unsigned int pack2(float a, float b) { return (unsigned int)f2bf(a) | ((unsigned int)f2bf(b) << 16); }
DEV unsigned int mul2bf(unsigned int a, unsigned int b) { return pack2(bflo(a)*bflo(b), bfhi(a)*bfhi(b)); }
DEV void unpack8(uint4 u, float* f) {
    f[0]=bflo(u.x); f[1]=bfhi(u.x); f[2]=bflo(u.y); f[3]=bfhi(u.y);
    f[4]=bflo(u.z); f[5]=bfhi(u.z); f[6]=bflo(u.w); f[7]=bfhi(u.w);
}

// ---------------------------------------------------------------------------
// K0: cast f32 -> bf16 (lt, rt, 4 match kernels) + rsq[b][r] = 1/||rt row|| (f64)
// grid: 8192 row-blocks (lt then rt) + 256 kernel-blocks; 128 threads
// ---------------------------------------------------------------------------
__global__ __launch_bounds__(128) void cast_kernel(const float* __restrict__ lt,
                                                   const float* __restrict__ rt,
                                                   const float* __restrict__ kf,
                                                   const float* __restrict__ kmp,
                                                   const float* __restrict__ ka,
                                                   const float* __restrict__ km,
                                                   unsigned short* __restrict__ ltb,
                                                   unsigned short* __restrict__ rtb,
                                                   unsigned short* __restrict__ kb,
                                                   double* __restrict__ rsq) {
    __shared__ double ws2[2];
    int bid = blockIdx.x, t = threadIdx.x;
    if (bid < 8192) {
        bool isRt = bid >= 4096;
        int row = isRt ? (bid - 4096) : bid;
        const float* src = (isRt ? rt : lt) + (size_t)row * 512;
        unsigned short* dst = (isRt ? rtb : ltb) + (size_t)row * 512;
        float4 v = *(const float4*)(src + t * 4);
        ushort4 o;
        o.x = f2bf(v.x); o.y = f2bf(v.y); o.z = f2bf(v.z); o.w = f2bf(v.w);
        *(ushort4*)(dst + t * 4) = o;
        if (isRt) {
            double s = (double)v.x * v.x + (double)v.y * v.y
                     + (double)v.z * v.z + (double)v.w * v.w;
            #pragma unroll
            for (int off = 1; off < 64; off <<= 1) s += __shfl_xor(s, off, 64);
            if ((t & 63) == 0) ws2[t >> 6] = s;
            __syncthreads();
            if (t == 0) rsq[row] = 1.0 / sqrt(ws2[0] + ws2[1]);
        }
    } else {
        int kbk = bid - 8192;               // 0..255
        int ksel = kbk >> 6;                // 64 blocks per kernel array
        const float* src = (ksel == 0) ? kf : (ksel == 1) ? kmp : (ksel == 2) ? ka : km;
        int off = (kbk & 63) * 512 + t * 4;
        float4 v = *(const float4*)(src + off);
        ushort4 o;
        o.x = f2bf(v.x); o.y = f2bf(v.y); o.z = f2bf(v.z); o.w = f2bf(v.w);
        *(ushort4*)(kb + ksel * 32768 + off) = o;
    }
}

// ---------------------------------------------------------------------------
// K1: transpose attn_w1 (512x128 f32) -> w1t (128x512 bf16)
// ---------------------------------------------------------------------------
__global__ __launch_bounds__(256) void transpose_w1(const float* __restrict__ w1,
                                                    unsigned short* __restrict__ w1t) {
    __shared__ float tile[32][33];
    int d0 = blockIdx.x * 32, a0 = blockIdx.y * 32;
    int t = threadIdx.x;
    int r = t >> 5, c = t & 31;
    #pragma unroll
    for (int i = 0; i < 32; i += 8)
        tile[r + i][c] = w1[(size_t)(d0 + r + i) * 128 + a0 + c];
    __syncthreads();
    #pragma unroll
    for (int i = 0; i < 32; i += 8)
        w1t[(size_t)(a0 + r + i) * 512 + d0 + c] = f2bf(tile[c][r + i]);
}

// ---------------------------------------------------------------------------
// K2: a_all[8192][128] = tanh(reps @ W1) (* diag for first 4096 rows), bf16
// ---------------------------------------------------------------------------
__global__ __launch_bounds__(256, 2) void proj_kernel(const unsigned short* __restrict__ ltb,
                                                      const unsigned short* __restrict__ rtb,
                                                      const unsigned short* __restrict__ w1t,
                                                      const float* __restrict__ diag,
                                                      unsigned short* __restrict__ a_all) {
    int R0 = blockIdx.x * 32;
    __shared__ __align__(16) unsigned short aS[32][72];
    __shared__ __align__(16) unsigned short bS[128][72];
    __shared__ float diagS[128];
    int t = threadIdx.x;
    int wave = t >> 6, lane = t & 63;
    int wl = wave & 1, wr = wave >> 1;
    int q = lane >> 4, col = lane & 15, kq = q * 8;
    if (t < 128) diagS[t] = diag[t];
    const unsigned short* src = (R0 < 4096) ? (ltb + (size_t)R0 * 512) : (rtb + (size_t)(R0 - 4096) * 512);
    float4v acc[4] = {};
    for (int k0 = 0; k0 < 512; k0 += 64) {
        {
            int row = t >> 3, cg = (t & 7) * 8;
            *(uint4*)&aS[row][cg] = *(const uint4*)(src + (size_t)row * 512 + k0 + cg);
        }
        #pragma unroll
        for (int it = 0; it < 4; ++it) {
            int id = it * 256 + t;
            int row = id >> 3, cg = (id & 7) * 8;
            *(uint4*)&bS[row][cg] = *(const uint4*)(w1t + (size_t)row * 512 + k0 + cg);
        }
        __syncthreads();
        #pragma unroll
        for (int kk = 0; kk < 64; kk += 32) {
            short8 af = *(const short8*)&aS[wl * 16 + col][kk + kq];
            #pragma unroll
            for (int j = 0; j < 4; ++j) {
                short8 bf = *(const short8*)&bS[wr * 64 + j * 16 + col][kk + kq];
                acc[j] = __builtin_amdgcn_mfma_f32_16x16x32_bf16(af, bf, acc[j], 0, 0, 0);
            }
        }
        __syncthreads();
    }
    bool isLt = (R0 < 4096);
    #pragma unroll
    for (int j = 0; j < 4; ++j)
        #pragma unroll
        for (int ii = 0; ii < 4; ++ii) {
            int rowl = wl * 16 + q * 4 + ii;
            int n = wr * 64 + j * 16 + col;
            float v = tanhf(acc[j][ii]);
            if (isLt) v *= diagS[n];
            a_all[((size_t)(R0 + rowl)) * 128 + n] = f2bf(v);
        }
}

// ---------------------------------------------------------------------------
// K3: argmax_r of (lt.rt)/||rt|| per (b,l) -- f64-exact accumulation
// WG = (b, 16 l), 512 threads: t = lg(2b) | rg(5b) | ds(2b)
// ---------------------------------------------------------------------------
__global__ __launch_bounds__(512, 2) void argmax_kernel(const float* __restrict__ lt,
                                                        const float* __restrict__ rtp,
                                                        const double* __restrict__ rsq,
                                                        int* __restrict__ idxout) {
    int b = blockIdx.x, lg8 = blockIdx.y;
    int L0 = lg8 * 16;
    __shared__ __align__(16) float ltS[16][512];
    __shared__ __align__(16) float buf[128 * 64];
    __shared__ double bwv[16][2];
    __shared__ int    bwi[16][2];
    int t = threadIdx.x;
    {
        int row = t >> 5, c0 = (t & 31) * 16;
        const float* src = lt + ((size_t)(b * 128 + L0 + row)) * 512 + c0;
        #pragma unroll
        for (int i = 0; i < 4; ++i)
            *(float4*)&ltS[row][c0 + i * 4] = *(const float4*)(src + i * 4);
    }
    int lg = t >> 7;
    int rg = (t >> 2) & 31;
    int ds = t & 3;
    double acc[4][4] = {{0.0}};
    for (int p = 0; p < 8; ++p) {
        __syncthreads();
        {
            int row = t >> 2, c0 = (t & 3) * 16;
            const float* src = rtp + ((size_t)(b * 128 + row)) * 512 + p * 64 + c0;
            float f[16];
            #pragma unroll
            for (int i = 0; i < 4; ++i)
                *(float4*)&f[i * 4] = *(const float4*)(src + i * 4);
            int g0 = (t & 3) * 2;
            int base = row * 64;
            int o0 = ((g0) ^ (row & 7)) * 8;
            int o1 = ((g0 + 1) ^ (row & 7)) * 8;
            #pragma unroll
            for (int i = 0; i < 8; ++i) buf[base + o0 + i] = f[i];
            #pragma unroll
            for (int i = 0; i < 8; ++i) buf[base + o1 + i] = f[8 + i];
        }
        __syncthreads();
        #pragma unroll
        for (int sub = 0; sub < 2; ++sub) {
            int dloc = ds * 16 + sub * 8;
            int dglob = p * 64 + dloc;
            double a[4][8];
            #pragma unroll
            for (int i = 0; i < 4; ++i)
                #pragma unroll
                for (int k = 0; k < 8; ++k) a[i][k] = (double)ltS[lg * 4 + i][dglob + k];
            int g = dloc >> 3;
            #pragma unroll
            for (int j = 0; j < 4; ++j) {
                int r = rg + j * 32;
                const float* rp = &buf[r * 64 + ((g ^ (r & 7)) * 8)];
                double rv[8];
                #pragma unroll
                for (int k = 0; k < 8; ++k) rv[k] = (double)rp[k];
                #pragma unroll
                for (int i = 0; i < 4; ++i)
                    #pragma unroll
                    for (int k = 0; k < 8; ++k)
                        acc[i][j] = fma(a[i][k], rv[k], acc[i][j]);
            }
        }
    }
    // sum partial dots over ds (lanes differing in bits 0-1)
    #pragma unroll
    for (int i = 0; i < 4; ++i)
        #pragma unroll
        for (int j = 0; j < 4; ++j) {
            acc[i][j] += __shfl_xor(acc[i][j], 1, 64);
            acc[i][j] += __shfl_xor(acc[i][j], 2, 64);
        }
    // per-lane best over the 4 r's
    double bv[4]; int bi[4];
    #pragma unroll
    for (int i = 0; i < 4; ++i) {
        double best = -1.0e300; int bidx = 0;
        #pragma unroll
        for (int j = 0; j < 4; ++j) {
            int r = rg + j * 32;
            double v = acc[i][j] * rsq[b * 128 + r];
            if (v > best || (v == best && r < bidx)) { best = v; bidx = r; }
        }
        bv[i] = best; bi[i] = bidx;
    }
    // max-butterfly over rg lanes (bits 2-5)
    #pragma unroll
    for (int off = 4; off < 64; off <<= 1) {
        #pragma unroll
        for (int i = 0; i < 4; ++i) {
            double ov = __shfl_xor(bv[i], off, 64);
            int    oi = __shfl_xor(bi[i], off, 64);
            if (ov > bv[i] || (ov == bv[i] && oi < bi[i])) { bv[i] = ov; bi[i] = oi; }
        }
    }
    int wave = t >> 6, lane = t & 63;
    if (lane == 0) {
        #pragma unroll
        for (int i = 0; i < 4; ++i) {
            bwv[lg * 4 + i][wave & 1] = bv[i];
            bwi[lg * 4 + i][wave & 1] = bi[i];
        }
    }
    __syncthreads();
    if (t < 16) {
        double v0 = bwv[t][0], v1 = bwv[t][1];
        int    i0 = bwi[t][0], i1 = bwi[t][1];
        int res = (v0 > v1 || (v0 == v1 && i0 < i1)) ? i0 : i1;
        idxout[b * 128 + L0 + t] = res;
    }
}

// ---------------------------------------------------------------------------
// K4: attentive att = softmax(a_lt @ a_rt^T) @ rt  -> attw (bf16)
// WG = (b, 16 l), 512 threads (8 waves)
// ---------------------------------------------------------------------------
__global__ __launch_bounds__(512, 2) void attn_kernel(const unsigned short* __restrict__ a_all,
                                                      const unsigned short* __restrict__ rtb,
                                                      unsigned short* __restrict__ attw) {
    int b = blockIdx.x, lg = blockIdx.y;
    int L0 = lg * 16;
    __shared__ __align__(16) unsigned short altS[16][136];
    __shared__ __align__(16) unsigned short artS[128][136];
    __shared__ __align__(16) unsigned short rtS[16][512];
    __shared__ float P[16][132];
    __shared__ float pmax[16][8];
    __shared__ float psum[16][8];
    int t = threadIdx.x;
    int wave = t >> 6, lane = t & 63;
    int q = lane >> 4, col = lane & 15, kq = q * 8;

    if (t < 256) {
        int row = t >> 4, c0 = (t & 15) * 8;
        *(uint4*)&altS[row][c0] = *(const uint4*)(a_all + ((size_t)(b * 128 + L0 + row)) * 128 + c0);
    }
    {
        int row = t >> 2, c0 = (t & 3) * 32;
        const unsigned short* src = a_all + ((size_t)(4096 + b * 128 + row)) * 128 + c0;
        #pragma unroll
        for (int i = 0; i < 4; ++i)
            *(uint4*)&artS[row][c0 + i * 8] = *(const uint4*)(src + i * 8);
    }
    __syncthreads();

    float4v acc = {};
    #pragma unroll
    for (int kk = 0; kk < 128; kk += 32) {
        short8 af = *(const short8*)&altS[col][kk + kq];
        short8 bf = *(const short8*)&artS[wave * 16 + col][kk + kq];
        acc = __builtin_amdgcn_mfma_f32_16x16x32_bf16(af, bf, acc, 0, 0, 0);
    }
    float m4[4], p4[4];
    #pragma unroll
    for (int ii = 0; ii < 4; ++ii) {
        float v = acc[ii];
        #pragma unroll
        for (int off = 1; off < 16; off <<= 1) v = fmaxf(v, __shfl_xor(v, off, 64));
        m4[ii] = v;
    }
    if (col == 0) {
        #pragma unroll
        for (int ii = 0; ii < 4; ++ii) pmax[q * 4 + ii][wave] = m4[ii];
    }
    __syncthreads();
    #pragma unroll
    for (int ii = 0; ii < 4; ++ii) {
        float M = pmax[q * 4 + ii][0];
        #pragma unroll
        for (int w = 1; w < 8; ++w) M = fmaxf(M, pmax[q * 4 + ii][w]);
        p4[ii] = expf(acc[ii] - M);
        float s = p4[ii];
        #pragma unroll
        for (int off = 1; off < 16; off <<= 1) s += __shfl_xor(s, off, 64);
        m4[ii] = s;
    }
    if (col == 0) {
        #pragma unroll
        for (int ii = 0; ii < 4; ++ii) psum[q * 4 + ii][wave] = m4[ii];
    }
    __syncthreads();
    #pragma unroll
    for (int ii = 0; ii < 4; ++ii) {
        float S = psum[q * 4 + ii][0] + psum[q * 4 + ii][1] + psum[q * 4 + ii][2] + psum[q * 4 + ii][3]
                + psum[q * 4 + ii][4] + psum[q * 4 + ii][5] + psum[q * 4 + ii][6] + psum[q * 4 + ii][7];
        P[q * 4 + ii][wave * 16 + col] = p4[ii] / S;
    }

    int l = t >> 5, cd = t & 31;
    float a8[2][8] = {{0.f}};
    for (int rcb = 0; rcb < 128; rcb += 16) {
        __syncthreads();
        {
            int row = t >> 5, c0 = (t & 31) * 16;
            const unsigned short* src = rtb + ((size_t)(b * 128 + rcb + row)) * 512 + c0;
            *(uint4*)&rtS[row][c0] = *(const uint4*)src;
            *(uint4*)&rtS[row][c0 + 8] = *(const uint4*)(src + 8);
        }
        __syncthreads();
        for (int rr = 0; rr < 16; ++rr) {
            float pr = P[l][rcb + rr];
            #pragma unroll
            for (int pass = 0; pass < 2; ++pass) {
                uint4 u = *(const uint4*)&rtS[rr][pass * 256 + cd * 8];
                float f[8]; unpack8(u, f);
                #pragma unroll
                for (int k = 0; k < 8; ++k) a8[pass][k] += pr * f[k];
            }
        }
    }
    size_t grow = (size_t)(b * 128 + L0 + l);
    #pragma unroll
    for (int pass = 0; pass < 2; ++pass) {
        uint4 o;
        o.x = pack2(a8[pass][0], a8[pass][1]);
        o.y = pack2(a8[pass][2], a8[pass][3]);
        o.z = pack2(a8[pass][4], a8[pass][5]);
        o.w = pack2(a8[pass][6], a8[pass][7]);
        *(uint4*)(attw + grow * 512 + pass * 256 + cd * 8) = o;
    }
}

// ---------------------------------------------------------------------------
// K5: max-pooling match. WG per (m, b): S = (lt*K_m) @ rt^T, out = tanh(max_r S)
// ---------------------------------------------------------------------------
__global__ __launch_bounds__(256, 2) void mpool_kernel(const unsigned short* __restrict__ ltb,
                                                       const unsigned short* __restrict__ rtb,
                                                       const unsigned short* __restrict__ kmb,
                                                       float* __restrict__ out) {
    int m = blockIdx.x, b = blockIdx.y;
    __shared__ __align__(16) unsigned short ltS[128][72];
    __shared__ __align__(16) unsigned short rtS[128][72];
    __shared__ float mx[128][2];
    int t = threadIdx.x;
    int wave = t >> 6, lane = t & 63;
    int wl = wave & 1, wr = wave >> 1;
    int q = lane >> 4, col = lane & 15, kq = q * 8;
    const unsigned short* ltp = ltb + (size_t)b * 128 * 512;
    const unsigned short* rtp = rtb + (size_t)b * 128 * 512;
    const unsigned short* kr = kmb + (size_t)m * 512;
    float4v acc[4][4] = {};
    int cg = (t & 7) * 8;
    for (int k0 = 0; k0 < 512; k0 += 64) {
        uint4 kv = *(const uint4*)(kr + k0 + cg);
        #pragma unroll
        for (int it = 0; it < 4; ++it) {
            int id = it * 256 + t;
            int row = id >> 3;
            uint4 lv = *(const uint4*)(ltp + (size_t)row * 512 + k0 + cg);
            uint4 rv = *(const uint4*)(rtp + (size_t)row * 512 + k0 + cg);
            uint4 sv;
            sv.x = mul2bf(lv.x, kv.x); sv.y = mul2bf(lv.y, kv.y);
            sv.z = mul2bf(lv.z, kv.z); sv.w = mul2bf(lv.w, kv.w);
            *(uint4*)&ltS[row][cg] = sv;
            *(uint4*)&rtS[row][cg] = rv;
        }
        __syncthreads();
        #pragma unroll
        for (int kk = 0; kk < 64; kk += 32) {
            short8 af[4], bfr[4];
            #pragma unroll
            for (int i = 0; i < 4; ++i) af[i] = *(const short8*)&ltS[wl * 64 + i * 16 + col][kk + kq];
            #pragma unroll
            for (int j = 0; j < 4; ++j) bfr[j] = *(const short8*)&rtS[wr * 64 + j * 16 + col][kk + kq];
            #pragma unroll
            for (int i = 0; i < 4; ++i)
                #pragma unroll
                for (int j = 0; j < 4; ++j)
                    acc[i][j] = __builtin_amdgcn_mfma_f32_16x16x32_bf16(af[i], bfr[j], acc[i][j], 0, 0, 0);
        }
        __syncthreads();
    }
    #pragma unroll
    for (int i = 0; i < 4; ++i)
        #pragma unroll
        for (int ii = 0; ii < 4; ++ii) {
            float v = fmaxf(fmaxf(acc[i][0][ii], acc[i][1][ii]), fmaxf(acc[i][2][ii], acc[i][3][ii]));
            #pragma unroll
            for (int off = 1; off < 16; off <<= 1) v = fmaxf(v, __shfl_xor(v, off, 64));
            if (col == 0) mx[wl * 64 + i * 16 + q * 4 + ii][wr] = v;
        }
    __syncthreads();
    if (t < 128)
        out[((size_t)(b * 128 + t)) * 259 + 65 + m] = tanhf(fmaxf(mx[t][0], mx[t][1]));
}

// ---------------------------------------------------------------------------
// K6: mp_match for full / attentive / maxatt (mode = blockIdx.z)
// ---------------------------------------------------------------------------
__global__ __launch_bounds__(256, 2) void mpmatch_kernel(const float* __restrict__ lt,
                                                         const unsigned short* __restrict__ rtb,
                                                         const float* __restrict__ hfw,
                                                         const float* __restrict__ hbw,
                                                         const unsigned short* __restrict__ kb,
                                                         const unsigned short* __restrict__ attw,
                                                         const int* __restrict__ idxp,
                                                         float* __restrict__ out) {
    int lg = blockIdx.x, b = blockIdx.y, mode = blockIdx.z;
    int L0 = lg * 16;
    __shared__ __align__(16) unsigned short prods[16][520];
    __shared__ __align__(16) unsigned short Ks[32][520];
    __shared__ float red[4][2][16][17];
    int t = threadIdx.x;
    int wave = t >> 6, lane = t & 63;
    int q = lane >> 4, col = lane & 15, kq = q * 8;

    const unsigned short* Kp = kb + (size_t)((mode == 0) ? 0 : (mode == 1) ? 2 * 32768 : 3 * 32768);
    int obase = (mode == 0) ? 0 : (mode == 1) ? 129 : 194;

    int l = t >> 4, c = t & 15;
    int grow = b * 128 + L0 + l;
    const float* ltrow = lt + (size_t)grow * 512;
    const unsigned short* avrow = 0;
    if (mode == 1) avrow = attw + (size_t)grow * 512;
    else if (mode == 2) avrow = rtb + ((size_t)(b * 128 + idxp[grow])) * 512;

    float csum = 0.f;
    #pragma unroll
    for (int pass = 0; pass < 4; ++pass) {
        int d0 = pass * 128 + c * 8;
        float lf[8], af[8], pf[8];
        *(float4*)&lf[0] = *(const float4*)(ltrow + d0);
        *(float4*)&lf[4] = *(const float4*)(ltrow + d0 + 4);
        if (mode == 0) {
            const float* h = (d0 < 256) ? (hfw + b * 256 + d0) : (hbw + b * 256 + d0 - 256);
            *(float4*)&af[0] = *(const float4*)h;
            *(float4*)&af[4] = *(const float4*)(h + 4);
        } else {
            uint4 av = *(const uint4*)(avrow + d0);
            unpack8(av, af);
        }
        #pragma unroll
        for (int k = 0; k < 8; ++k) { pf[k] = lf[k] * af[k]; csum += pf[k]; }
        uint4 o;
        o.x = pack2(pf[0], pf[1]); o.y = pack2(pf[2], pf[3]);
        o.z = pack2(pf[4], pf[5]); o.w = pack2(pf[6], pf[7]);
        *(uint4*)&prods[l][d0] = o;
    }
    #pragma unroll
    for (int off = 1; off < 16; off <<= 1) csum += __shfl_xor(csum, off, 64);
    if (c == 0) out[(size_t)grow * 259 + obase] = tanhf(csum);

    for (int half = 0; half < 2; ++half) {
        {
            int row = t >> 3, c0 = (t & 7) * 64;
            const unsigned short* src = Kp + ((size_t)(half * 32 + row)) * 512 + c0;
            #pragma unroll
            for (int i = 0; i < 8; ++i)
                *(uint4*)&Ks[row][c0 + i * 8] = *(const uint4*)(src + i * 8);
        }
        __syncthreads();
        float4v acc[2] = {};
        #pragma unroll
        for (int kk = 0; kk < 128; kk += 32) {
            short8 af = *(const short8*)&prods[col][wave * 128 + kk + kq];
            #pragma unroll
            for (int j = 0; j < 2; ++j) {
                short8 bf = *(const short8*)&Ks[j * 16 + col][wave * 128 + kk + kq];
                acc[j] = __builtin_amdgcn_mfma_f32_16x16x32_bf16(af, bf, acc[j], 0, 0, 0);
            }
        }
        #pragma unroll
        for (int j = 0; j < 2; ++j)
            #pragma unroll
            for (int ii = 0; ii < 4; ++ii)
                red[wave][j][q * 4 + ii][col] = acc[j][ii];
        __syncthreads();
        for (int o = t; o < 512; o += 256) {
            int ll = o >> 5, jm = o & 31;
            int j = jm >> 4, mc = jm & 15;
            float s = red[0][j][ll][mc] + red[1][j][ll][mc] + red[2][j][ll][mc] + red[3][j][ll][mc];
            out[((size_t)(b * 128 + L0 + ll)) * 259 + obase + 1 + half * 32 + jm] = tanhf(s);
        }
        __syncthreads();
    }
}

// ---------------------------------------------------------------------------
extern "C" void kernel_launch(void* const* d_in, const int* in_sizes, int n_in,
                              void* d_out, int out_size, void* d_ws, size_t ws_size,
                              hipStream_t stream) {
    const float* lt  = (const float*)d_in[0];
    const float* rt  = (const float*)d_in[3];
    const float* hfw = (const float*)d_in[4];
    const float* hbw = (const float*)d_in[5];
    const float* kf  = (const float*)d_in[6];
    const float* kmp = (const float*)d_in[7];
    const float* w1  = (const float*)d_in[8];
    const float* dia = (const float*)d_in[9];
    const float* ka  = (const float*)d_in[10];
    const float* km  = (const float*)d_in[11];
    float* out = (float*)d_out;

    char* wsb = (char*)d_ws;
    unsigned short* ltb16 = (unsigned short*)(wsb);                        // 4 MB
    unsigned short* rtb16 = (unsigned short*)(wsb + 4194304);              // 4 MB
    unsigned short* kb16  = (unsigned short*)(wsb + 8388608);              // 256 KB
    unsigned short* w1t   = (unsigned short*)(wsb + 8650752);              // 128 KB
    unsigned short* a_all = (unsigned short*)(wsb + 8781824);              // 2 MB
    unsigned short* attw  = (unsigned short*)(wsb + 10878976);             // 4 MB
    double*         rsq   = (double*)(wsb + 15073280);                     // 32 KB
    int*            idx   = (int*)(wsb + 15106048);                        // 16 KB

    cast_kernel<<<8448, 128, 0, stream>>>(lt, rt, kf, kmp, ka, km, ltb16, rtb16, kb16, rsq);
    transpose_w1<<<dim3(16, 4), 256, 0, stream>>>(w1, w1t);
    proj_kernel<<<dim3(256), 256, 0, stream>>>(ltb16, rtb16, w1t, dia, a_all);
    argmax_kernel<<<dim3(32, 8), 512, 0, stream>>>(lt, rt, rsq, idx);
    attn_kernel<<<dim3(32, 8), 512, 0, stream>>>(a_all, rtb16, attw);
    mpool_kernel<<<dim3(64, 32), 256, 0, stream>>>(ltb16, rtb16, kb16 + 32768, out);
    mpmatch_kernel<<<dim3(8, 32, 3), 256, 0, stream>>>(lt, rtb16, hfw, hbw, kb16, attw, idx, out);
}

// Round 3
// 213.218 us; speedup vs baseline: 1.0137x; 1.0137x over previous
//
#include <hip/hip_runtime.h>
#include <hip/hip_bf16.h>
#include <math.h>
#include <stdint.h>

typedef __attribute__((ext_vector_type(8))) short short8;
typedef __attribute__((ext_vector_type(4))) float float4v;

#define DEV static __device__ __forceinline__

DEV float bflo(unsigned int u) { union { unsigned int i; float f; } v; v.i = u << 16; return v.f; }
DEV float bfhi(unsigned int u) { union { unsigned int i; float f; } v; v.i = u & 0xffff0000u; return v.f; }
DEV unsigned short f2bf(float f) {
    union { float f; unsigned int i; } v; v.f = f;
    unsigned int x = v.i;
    return (unsigned short)((x + 0x7fffu + ((x >> 16) & 1u)) >> 16);
}
DEV unsigned int pack2(float a, float b) { return (unsigned int)f2bf(a) | ((unsigned int)f2bf(b) << 16); }
#if __has_builtin(__builtin_amdgcn_cvt_pk_bf16_f32)
DEV unsigned int pack2_fast(float a, float b) {
    typedef __attribute__((ext_vector_type(2))) short short2v;
    short2v r = __builtin_amdgcn_cvt_pk_bf16_f32(a, b);
    union { short2v s; unsigned int u; } v; v.s = r; return v.u;
}
#else
DEV unsigned int pack2_fast(float a, float b) { return pack2(a, b); }
#endif
DEV unsigned int mul2bf(unsigned int a, unsigned int b) { return pack2(bflo(a)*bflo(b), bfhi(a)*bfhi(b)); }
DEV void unpack8(uint4 u, float* f) {
    f[0]=bflo(u.x); f[1]=bfhi(u.x); f[2]=bflo(u.y); f[3]=bfhi(u.y);
    f[4]=bflo(u.z); f[5]=bfhi(u.z); f[6]=bflo(u.w); f[7]=bfhi(u.w);
}

// ---------------------------------------------------------------------------
// K0: cast f32 -> bf16 (lt, rt, 4 match kernels) + rsq[b][r] = 1/||rt row|| (f64)
// ---------------------------------------------------------------------------
__global__ __launch_bounds__(128) void cast_kernel(const float* __restrict__ lt,
                                                   const float* __restrict__ rt,
                                                   const float* __restrict__ kf,
                                                   const float* __restrict__ kmp,
                                                   const float* __restrict__ ka,
                                                   const float* __restrict__ km,
                                                   unsigned short* __restrict__ ltb,
                                                   unsigned short* __restrict__ rtb,
                                                   unsigned short* __restrict__ kb,
                                                   double* __restrict__ rsq) {
    __shared__ double ws2[2];
    int bid = blockIdx.x, t = threadIdx.x;
    if (bid < 8192) {
        bool isRt = bid >= 4096;
        int row = isRt ? (bid - 4096) : bid;
        const float* src = (isRt ? rt : lt) + (size_t)row * 512;
        unsigned short* dst = (isRt ? rtb : ltb) + (size_t)row * 512;
        float4 v = *(const float4*)(src + t * 4);
        ushort4 o;
        o.x = f2bf(v.x); o.y = f2bf(v.y); o.z = f2bf(v.z); o.w = f2bf(v.w);
        *(ushort4*)(dst + t * 4) = o;
        if (isRt) {
            double s = (double)v.x * v.x + (double)v.y * v.y
                     + (double)v.z * v.z + (double)v.w * v.w;
            #pragma unroll
            for (int off = 1; off < 64; off <<= 1) s += __shfl_xor(s, off, 64);
            if ((t & 63) == 0) ws2[t >> 6] = s;
            __syncthreads();
            if (t == 0) rsq[row] = 1.0 / sqrt(ws2[0] + ws2[1]);
        }
    } else {
        int kbk = bid - 8192;               // 0..255
        int ksel = kbk >> 6;
        const float* src = (ksel == 0) ? kf : (ksel == 1) ? kmp : (ksel == 2) ? ka : km;
        int off = (kbk & 63) * 512 + t * 4;
        float4 v = *(const float4*)(src + off);
        ushort4 o;
        o.x = f2bf(v.x); o.y = f2bf(v.y); o.z = f2bf(v.z); o.w = f2bf(v.w);
        *(ushort4*)(kb + ksel * 32768 + off) = o;
    }
}

// ---------------------------------------------------------------------------
// K1: transpose attn_w1 (512x128 f32) -> w1t (128x512 bf16)
// ---------------------------------------------------------------------------
__global__ __launch_bounds__(256) void transpose_w1(const float* __restrict__ w1,
                                                    unsigned short* __restrict__ w1t) {
    __shared__ float tile[32][33];
    int d0 = blockIdx.x * 32, a0 = blockIdx.y * 32;
    int t = threadIdx.x;
    int r = t >> 5, c = t & 31;
    #pragma unroll
    for (int i = 0; i < 32; i += 8)
        tile[r + i][c] = w1[(size_t)(d0 + r + i) * 128 + a0 + c];
    __syncthreads();
    #pragma unroll
    for (int i = 0; i < 32; i += 8)
        w1t[(size_t)(a0 + r + i) * 512 + d0 + c] = f2bf(tile[c][r + i]);
}

// ---------------------------------------------------------------------------
// K2: a_all[8192][128] = tanh(reps @ W1) (* diag for first 4096 rows), bf16
// ---------------------------------------------------------------------------
__global__ __launch_bounds__(256, 2) void proj_kernel(const unsigned short* __restrict__ ltb,
                                                      const unsigned short* __restrict__ rtb,
                                                      const unsigned short* __restrict__ w1t,
                                                      const float* __restrict__ diag,
                                                      unsigned short* __restrict__ a_all) {
    int R0 = blockIdx.x * 32;
    __shared__ __align__(16) unsigned short aS[32][72];
    __shared__ __align__(16) unsigned short bS[128][72];
    __shared__ float diagS[128];
    int t = threadIdx.x;
    int wave = t >> 6, lane = t & 63;
    int wl = wave & 1, wr = wave >> 1;
    int q = lane >> 4, col = lane & 15, kq = q * 8;
    if (t < 128) diagS[t] = diag[t];
    const unsigned short* src = (R0 < 4096) ? (ltb + (size_t)R0 * 512) : (rtb + (size_t)(R0 - 4096) * 512);
    float4v acc[4] = {};
    for (int k0 = 0; k0 < 512; k0 += 64) {
        {
            int row = t >> 3, cg = (t & 7) * 8;
            *(uint4*)&aS[row][cg] = *(const uint4*)(src + (size_t)row * 512 + k0 + cg);
        }
        #pragma unroll
        for (int it = 0; it < 4; ++it) {
            int id = it * 256 + t;
            int row = id >> 3, cg = (id & 7) * 8;
            *(uint4*)&bS[row][cg] = *(const uint4*)(w1t + (size_t)row * 512 + k0 + cg);
        }
        __syncthreads();
        #pragma unroll
        for (int kk = 0; kk < 64; kk += 32) {
            short8 af = *(const short8*)&aS[wl * 16 + col][kk + kq];
            #pragma unroll
            for (int j = 0; j < 4; ++j) {
                short8 bf = *(const short8*)&bS[wr * 64 + j * 16 + col][kk + kq];
                acc[j] = __builtin_amdgcn_mfma_f32_16x16x32_bf16(af, bf, acc[j], 0, 0, 0);
            }
        }
        __syncthreads();
    }
    bool isLt = (R0 < 4096);
    #pragma unroll
    for (int j = 0; j < 4; ++j)
        #pragma unroll
        for (int ii = 0; ii < 4; ++ii) {
            int rowl = wl * 16 + q * 4 + ii;
            int n = wr * 64 + j * 16 + col;
            float v = tanhf(acc[j][ii]);
            if (isLt) v *= diagS[n];
            a_all[((size_t)(R0 + rowl)) * 128 + n] = f2bf(v);
        }
}

// ---------------------------------------------------------------------------
// K3: argmax_r of (lt.rt)/||rt|| per (b,l) -- f64-exact accumulation
// ---------------------------------------------------------------------------
__global__ __launch_bounds__(512, 2) void argmax_kernel(const float* __restrict__ lt,
                                                        const float* __restrict__ rtp,
                                                        const double* __restrict__ rsq,
                                                        int* __restrict__ idxout) {
    int b = blockIdx.x, lg8 = blockIdx.y;
    int L0 = lg8 * 16;
    __shared__ __align__(16) float ltS[16][512];
    __shared__ __align__(16) float buf[128 * 64];
    __shared__ double bwv[16][2];
    __shared__ int    bwi[16][2];
    int t = threadIdx.x;
    {
        int row = t >> 5, c0 = (t & 31) * 16;
        const float* src = lt + ((size_t)(b * 128 + L0 + row)) * 512 + c0;
        #pragma unroll
        for (int i = 0; i < 4; ++i)
            *(float4*)&ltS[row][c0 + i * 4] = *(const float4*)(src + i * 4);
    }
    int lg = t >> 7;
    int rg = (t >> 2) & 31;
    int ds = t & 3;
    double acc[4][4] = {{0.0}};
    for (int p = 0; p < 8; ++p) {
        __syncthreads();
        {
            int row = t >> 2, c0 = (t & 3) * 16;
            const float* src = rtp + ((size_t)(b * 128 + row)) * 512 + p * 64 + c0;
            float f[16];
            #pragma unroll
            for (int i = 0; i < 4; ++i)
                *(float4*)&f[i * 4] = *(const float4*)(src + i * 4);
            int g0 = (t & 3) * 2;
            int base = row * 64;
            int o0 = ((g0) ^ (row & 7)) * 8;
            int o1 = ((g0 + 1) ^ (row & 7)) * 8;
            #pragma unroll
            for (int i = 0; i < 8; ++i) buf[base + o0 + i] = f[i];
            #pragma unroll
            for (int i = 0; i < 8; ++i) buf[base + o1 + i] = f[8 + i];
        }
        __syncthreads();
        #pragma unroll
        for (int sub = 0; sub < 2; ++sub) {
            int dloc = ds * 16 + sub * 8;
            int dglob = p * 64 + dloc;
            double a[4][8];
            #pragma unroll
            for (int i = 0; i < 4; ++i)
                #pragma unroll
                for (int k = 0; k < 8; ++k) a[i][k] = (double)ltS[lg * 4 + i][dglob + k];
            int g = dloc >> 3;
            #pragma unroll
            for (int j = 0; j < 4; ++j) {
                int r = rg + j * 32;
                const float* rp = &buf[r * 64 + ((g ^ (r & 7)) * 8)];
                double rv[8];
                #pragma unroll
                for (int k = 0; k < 8; ++k) rv[k] = (double)rp[k];
                #pragma unroll
                for (int i = 0; i < 4; ++i)
                    #pragma unroll
                    for (int k = 0; k < 8; ++k)
                        acc[i][j] = fma(a[i][k], rv[k], acc[i][j]);
            }
        }
    }
    #pragma unroll
    for (int i = 0; i < 4; ++i)
        #pragma unroll
        for (int j = 0; j < 4; ++j) {
            acc[i][j] += __shfl_xor(acc[i][j], 1, 64);
            acc[i][j] += __shfl_xor(acc[i][j], 2, 64);
        }
    double bv[4]; int bi[4];
    #pragma unroll
    for (int i = 0; i < 4; ++i) {
        double best = -1.0e300; int bidx = 0;
        #pragma unroll
        for (int j = 0; j < 4; ++j) {
            int r = rg + j * 32;
            double v = acc[i][j] * rsq[b * 128 + r];
            if (v > best || (v == best && r < bidx)) { best = v; bidx = r; }
        }
        bv[i] = best; bi[i] = bidx;
    }
    #pragma unroll
    for (int off = 4; off < 64; off <<= 1) {
        #pragma unroll
        for (int i = 0; i < 4; ++i) {
            double ov = __shfl_xor(bv[i], off, 64);
            int    oi = __shfl_xor(bi[i], off, 64);
            if (ov > bv[i] || (ov == bv[i] && oi < bi[i])) { bv[i] = ov; bi[i] = oi; }
        }
    }
    int wave = t >> 6, lane = t & 63;
    if (lane == 0) {
        #pragma unroll
        for (int i = 0; i < 4; ++i) {
            bwv[lg * 4 + i][wave & 1] = bv[i];
            bwi[lg * 4 + i][wave & 1] = bi[i];
        }
    }
    __syncthreads();
    if (t < 16) {
        double v0 = bwv[t][0], v1 = bwv[t][1];
        int    i0 = bwi[t][0], i1 = bwi[t][1];
        int res = (v0 > v1 || (v0 == v1 && i0 < i1)) ? i0 : i1;
        idxout[b * 128 + L0 + t] = res;
    }
}

// ---------------------------------------------------------------------------
// K4: attentive att = softmax(a_lt @ a_rt^T) @ rt  -> attw (bf16)
// ---------------------------------------------------------------------------
__global__ __launch_bounds__(512, 2) void attn_kernel(const unsigned short* __restrict__ a_all,
                                                      const unsigned short* __restrict__ rtb,
                                                      unsigned short* __restrict__ attw) {
    int b = blockIdx.x, lg = blockIdx.y;
    int L0 = lg * 16;
    __shared__ __align__(16) unsigned short altS[16][136];
    __shared__ __align__(16) unsigned short artS[128][136];
    __shared__ __align__(16) unsigned short rtS[16][512];
    __shared__ float P[16][132];
    __shared__ float pmax[16][8];
    __shared__ float psum[16][8];
    int t = threadIdx.x;
    int wave = t >> 6, lane = t & 63;
    int q = lane >> 4, col = lane & 15, kq = q * 8;

    if (t < 256) {
        int row = t >> 4, c0 = (t & 15) * 8;
        *(uint4*)&altS[row][c0] = *(const uint4*)(a_all + ((size_t)(b * 128 + L0 + row)) * 128 + c0);
    }
    {
        int row = t >> 2, c0 = (t & 3) * 32;
        const unsigned short* src = a_all + ((size_t)(4096 + b * 128 + row)) * 128 + c0;
        #pragma unroll
        for (int i = 0; i < 4; ++i)
            *(uint4*)&artS[row][c0 + i * 8] = *(const uint4*)(src + i * 8);
    }
    __syncthreads();

    float4v acc = {};
    #pragma unroll
    for (int kk = 0; kk < 128; kk += 32) {
        short8 af = *(const short8*)&altS[col][kk + kq];
        short8 bf = *(const short8*)&artS[wave * 16 + col][kk + kq];
        acc = __builtin_amdgcn_mfma_f32_16x16x32_bf16(af, bf, acc, 0, 0, 0);
    }
    float m4[4], p4[4];
    #pragma unroll
    for (int ii = 0; ii < 4; ++ii) {
        float v = acc[ii];
        #pragma unroll
        for (int off = 1; off < 16; off <<= 1) v = fmaxf(v, __shfl_xor(v, off, 64));
        m4[ii] = v;
    }
    if (col == 0) {
        #pragma unroll
        for (int ii = 0; ii < 4; ++ii) pmax[q * 4 + ii][wave] = m4[ii];
    }
    __syncthreads();
    #pragma unroll
    for (int ii = 0; ii < 4; ++ii) {
        float M = pmax[q * 4 + ii][0];
        #pragma unroll
        for (int w = 1; w < 8; ++w) M = fmaxf(M, pmax[q * 4 + ii][w]);
        p4[ii] = expf(acc[ii] - M);
        float s = p4[ii];
        #pragma unroll
        for (int off = 1; off < 16; off <<= 1) s += __shfl_xor(s, off, 64);
        m4[ii] = s;
    }
    if (col == 0) {
        #pragma unroll
        for (int ii = 0; ii < 4; ++ii) psum[q * 4 + ii][wave] = m4[ii];
    }
    __syncthreads();
    #pragma unroll
    for (int ii = 0; ii < 4; ++ii) {
        float S = psum[q * 4 + ii][0] + psum[q * 4 + ii][1] + psum[q * 4 + ii][2] + psum[q * 4 + ii][3]
                + psum[q * 4 + ii][4] + psum[q * 4 + ii][5] + psum[q * 4 + ii][6] + psum[q * 4 + ii][7];
        P[q * 4 + ii][wave * 16 + col] = p4[ii] / S;
    }

    int l = t >> 5, cd = t & 31;
    float a8[2][8] = {{0.f}};
    for (int rcb = 0; rcb < 128; rcb += 16) {
        __syncthreads();
        {
            int row = t >> 5, c0 = (t & 31) * 16;
            const unsigned short* src = rtb + ((size_t)(b * 128 + rcb + row)) * 512 + c0;
            *(uint4*)&rtS[row][c0] = *(const uint4*)src;
            *(uint4*)&rtS[row][c0 + 8] = *(const uint4*)(src + 8);
        }
        __syncthreads();
        for (int rr = 0; rr < 16; ++rr) {
            float pr = P[l][rcb + rr];
            #pragma unroll
            for (int pass = 0; pass < 2; ++pass) {
                uint4 u = *(const uint4*)&rtS[rr][pass * 256 + cd * 8];
                float f[8]; unpack8(u, f);
                #pragma unroll
                for (int k = 0; k < 8; ++k) a8[pass][k] += pr * f[k];
            }
        }
    }
    size_t grow = (size_t)(b * 128 + L0 + l);
    #pragma unroll
    for (int pass = 0; pass < 2; ++pass) {
        uint4 o;
        o.x = pack2(a8[pass][0], a8[pass][1]);
        o.y = pack2(a8[pass][2], a8[pass][3]);
        o.z = pack2(a8[pass][4], a8[pass][5]);
        o.w = pack2(a8[pass][6], a8[pass][7]);
        *(uint4*)(attw + grow * 512 + pass * 256 + cd * 8) = o;
    }
}

// ---------------------------------------------------------------------------
// K5: max-pooling match, 2 perspectives per WG.
// WG=(m-pair, b), 4 waves: wave = (wm = wave>>1, wl = wave&1); each wave
// computes 64l x 128r for its m, maxes over r, stores directly.
// ---------------------------------------------------------------------------
__global__ __launch_bounds__(256, 2) void mpool_kernel(const unsigned short* __restrict__ ltb,
                                                       const unsigned short* __restrict__ rtb,
                                                       const unsigned short* __restrict__ kmb,
                                                       float* __restrict__ out) {
    int mp = blockIdx.x, b = blockIdx.y;
    __shared__ __align__(16) unsigned short ltS[2][128][72];
    __shared__ __align__(16) unsigned short rtS[128][72];
    int t = threadIdx.x;
    int wave = t >> 6, lane = t & 63;
    int wl = wave & 1;     // l half
    int wm = wave >> 1;    // m within pair
    int q = lane >> 4, col = lane & 15, kq = q * 8;
    const unsigned short* ltp = ltb + (size_t)b * 65536;
    const unsigned short* rtp = rtb + (size_t)b * 65536;
    const unsigned short* kr0 = kmb + (size_t)(2 * mp) * 512;
    float4v acc[4][8] = {};
    int srow = t >> 3;           // 0..31
    int cg = (t & 7) * 8;        // 0..56
    for (int k0 = 0; k0 < 512; k0 += 64) {
        uint4 kv0 = *(const uint4*)(kr0 + k0 + cg);
        uint4 kv1 = *(const uint4*)(kr0 + 512 + k0 + cg);
        float k0f[8], k1f[8];
        unpack8(kv0, k0f); unpack8(kv1, k1f);
        #pragma unroll
        for (int it = 0; it < 4; ++it) {
            int row = srow + it * 32;
            uint4 lv = *(const uint4*)(ltp + (size_t)row * 512 + k0 + cg);
            uint4 rv = *(const uint4*)(rtp + (size_t)row * 512 + k0 + cg);
            float lf[8]; unpack8(lv, lf);
            uint4 s0, s1;
            s0.x = pack2_fast(lf[0] * k0f[0], lf[1] * k0f[1]);
            s0.y = pack2_fast(lf[2] * k0f[2], lf[3] * k0f[3]);
            s0.z = pack2_fast(lf[4] * k0f[4], lf[5] * k0f[5]);
            s0.w = pack2_fast(lf[6] * k0f[6], lf[7] * k0f[7]);
            s1.x = pack2_fast(lf[0] * k1f[0], lf[1] * k1f[1]);
            s1.y = pack2_fast(lf[2] * k1f[2], lf[3] * k1f[3]);
            s1.z = pack2_fast(lf[4] * k1f[4], lf[5] * k1f[5]);
            s1.w = pack2_fast(lf[6] * k1f[6], lf[7] * k1f[7]);
            *(uint4*)&ltS[0][row][cg] = s0;
            *(uint4*)&ltS[1][row][cg] = s1;
            *(uint4*)&rtS[row][cg] = rv;
        }
        __syncthreads();
        #pragma unroll
        for (int kk = 0; kk < 64; kk += 32) {
            short8 af[4];
            #pragma unroll
            for (int i = 0; i < 4; ++i)
                af[i] = *(const short8*)&ltS[wm][wl * 64 + i * 16 + col][kk + kq];
            #pragma unroll
            for (int j = 0; j < 8; ++j) {
                short8 bfr = *(const short8*)&rtS[j * 16 + col][kk + kq];
                #pragma unroll
                for (int i = 0; i < 4; ++i)
                    acc[i][j] = __builtin_amdgcn_mfma_f32_16x16x32_bf16(af[i], bfr, acc[i][j], 0, 0, 0);
            }
        }
        __syncthreads();
    }
    int m = 2 * mp + wm;
    #pragma unroll
    for (int i = 0; i < 4; ++i)
        #pragma unroll
        for (int ii = 0; ii < 4; ++ii) {
            float v = acc[i][0][ii];
            #pragma unroll
            for (int j = 1; j < 8; ++j) v = fmaxf(v, acc[i][j][ii]);
            #pragma unroll
            for (int off = 1; off < 16; off <<= 1) v = fmaxf(v, __shfl_xor(v, off, 64));
            if (col == 0)
                out[((size_t)(b * 128 + wl * 64 + i * 16 + q * 4 + ii)) * 259 + 65 + m] = tanhf(v);
        }
}

// ---------------------------------------------------------------------------
// K6: mp_match for full / attentive / maxatt (mode = blockIdx.z)
// ---------------------------------------------------------------------------
__global__ __launch_bounds__(256, 2) void mpmatch_kernel(const float* __restrict__ lt,
                                                         const unsigned short* __restrict__ rtb,
                                                         const float* __restrict__ hfw,
                                                         const float* __restrict__ hbw,
                                                         const unsigned short* __restrict__ kb,
                                                         const unsigned short* __restrict__ attw,
                                                         const int* __restrict__ idxp,
                                                         float* __restrict__ out) {
    int lg = blockIdx.x, b = blockIdx.y, mode = blockIdx.z;
    int L0 = lg * 16;
    __shared__ __align__(16) unsigned short prods[16][520];
    __shared__ __align__(16) unsigned short Ks[32][520];
    __shared__ float red[4][2][16][17];
    int t = threadIdx.x;
    int wave = t >> 6, lane = t & 63;
    int q = lane >> 4, col = lane & 15, kq = q * 8;

    const unsigned short* Kp = kb + (size_t)((mode == 0) ? 0 : (mode == 1) ? 2 * 32768 : 3 * 32768);
    int obase = (mode == 0) ? 0 : (mode == 1) ? 129 : 194;

    int l = t >> 4, c = t & 15;
    int grow = b * 128 + L0 + l;
    const float* ltrow = lt + (size_t)grow * 512;
    const unsigned short* avrow = 0;
    if (mode == 1) avrow = attw + (size_t)grow * 512;
    else if (mode == 2) avrow = rtb + ((size_t)(b * 128 + idxp[grow])) * 512;

    float csum = 0.f;
    #pragma unroll
    for (int pass = 0; pass < 4; ++pass) {
        int d0 = pass * 128 + c * 8;
        float lf[8], af[8], pf[8];
        *(float4*)&lf[0] = *(const float4*)(ltrow + d0);
        *(float4*)&lf[4] = *(const float4*)(ltrow + d0 + 4);
        if (mode == 0) {
            const float* h = (d0 < 256) ? (hfw + b * 256 + d0) : (hbw + b * 256 + d0 - 256);
            *(float4*)&af[0] = *(const float4*)h;
            *(float4*)&af[4] = *(const float4*)(h + 4);
        } else {
            uint4 av = *(const uint4*)(avrow + d0);
            unpack8(av, af);
        }
        #pragma unroll
        for (int k = 0; k < 8; ++k) { pf[k] = lf[k] * af[k]; csum += pf[k]; }
        uint4 o;
        o.x = pack2(pf[0], pf[1]); o.y = pack2(pf[2], pf[3]);
        o.z = pack2(pf[4], pf[5]); o.w = pack2(pf[6], pf[7]);
        *(uint4*)&prods[l][d0] = o;
    }
    #pragma unroll
    for (int off = 1; off < 16; off <<= 1) csum += __shfl_xor(csum, off, 64);
    if (c == 0) out[(size_t)grow * 259 + obase] = tanhf(csum);

    for (int half = 0; half < 2; ++half) {
        {
            int row = t >> 3, c0 = (t & 7) * 64;
            const unsigned short* src = Kp + ((size_t)(half * 32 + row)) * 512 + c0;
            #pragma unroll
            for (int i = 0; i < 8; ++i)
                *(uint4*)&Ks[row][c0 + i * 8] = *(const uint4*)(src + i * 8);
        }
        __syncthreads();
        float4v acc[2] = {};
        #pragma unroll
        for (int kk = 0; kk < 128; kk += 32) {
            short8 af = *(const short8*)&prods[col][wave * 128 + kk + kq];
            #pragma unroll
            for (int j = 0; j < 2; ++j) {
                short8 bf = *(const short8*)&Ks[j * 16 + col][wave * 128 + kk + kq];
                acc[j] = __builtin_amdgcn_mfma_f32_16x16x32_bf16(af, bf, acc[j], 0, 0, 0);
            }
        }
        #pragma unroll
        for (int j = 0; j < 2; ++j)
            #pragma unroll
            for (int ii = 0; ii < 4; ++ii)
                red[wave][j][q * 4 + ii][col] = acc[j][ii];
        __syncthreads();
        for (int o = t; o < 512; o += 256) {
            int ll = o >> 5, jm = o & 31;
            int j = jm >> 4, mc = jm & 15;
            float s = red[0][j][ll][mc] + red[1][j][ll][mc] + red[2][j][ll][mc] + red[3][j][ll][mc];
            out[((size_t)(b * 128 + L0 + ll)) * 259 + obase + 1 + half * 32 + jm] = tanhf(s);
        }
        __syncthreads();
    }
}

// ---------------------------------------------------------------------------
extern "C" void kernel_launch(void* const* d_in, const int* in_sizes, int n_in,
                              void* d_out, int out_size, void* d_ws, size_t ws_size,
                              hipStream_t stream) {
    const float* lt  = (const float*)d_in[0];
    const float* rt  = (const float*)d_in[3];
    const float* hfw = (const float*)d_in[4];
    const float* hbw = (const float*)d_in[5];
    const float* kf  = (const float*)d_in[6];
    const float* kmp = (const float*)d_in[7];
    const float* w1  = (const float*)d_in[8];
    const float* dia = (const float*)d_in[9];
    const float* ka  = (const float*)d_in[10];
    const float* km  = (const float*)d_in[11];
    float* out = (float*)d_out;

    char* wsb = (char*)d_ws;
    unsigned short* ltb16 = (unsigned short*)(wsb);                        // 4 MB
    unsigned short* rtb16 = (unsigned short*)(wsb + 4194304);              // 4 MB
    unsigned short* kb16  = (unsigned short*)(wsb + 8388608);              // 256 KB
    unsigned short* w1t   = (unsigned short*)(wsb + 8650752);              // 128 KB
    unsigned short* a_all = (unsigned short*)(wsb + 8781824);              // 2 MB
    unsigned short* attw  = (unsigned short*)(wsb + 10878976);             // 4 MB
    double*         rsq   = (double*)(wsb + 15073280);                     // 32 KB
    int*            idx   = (int*)(wsb + 15106048);                        // 16 KB

    cast_kernel<<<8448, 128, 0, stream>>>(lt, rt, kf, kmp, ka, km, ltb16, rtb16, kb16, rsq);
    transpose_w1<<<dim3(16, 4), 256, 0, stream>>>(w1, w1t);
    proj_kernel<<<dim3(256), 256, 0, stream>>>(ltb16, rtb16, w1t, dia, a_all);
    argmax_kernel<<<dim3(32, 8), 512, 0, stream>>>(lt, rt, rsq, idx);
    attn_kernel<<<dim3(32, 8), 512, 0, stream>>>(a_all, rtb16, attw);
    mpool_kernel<<<dim3(32, 32), 256, 0, stream>>>(ltb16, rtb16, kb16 + 32768, out);
    mpmatch_kernel<<<dim3(8, 32, 3), 256, 0, stream>>>(lt, rtb16, hfw, hbw, kb16, attw, idx, out);
}